// Round 8
// baseline (302.128 us; speedup 1.0000x reference)
//
#include <hip/hip_runtime.h>
#include <hip/hip_cooperative_groups.h>
#include <math.h>

// NeuralMemory: chunked-parallel decaying rank-1 memory scan, all-MFMA version.
//   S_t = decay*S_{t-1} + s_t * v_t k_t^T ;  out_t = q_t^T S_{t-1}
// Chunk C=128, NC=16, b=4, s=2048, d_model=1024, d_mem=256.
//
//  1. prep:      x -> x16 ; gate = sigmoid(x@Wg+bg) ; Wk|Wv|Wq -> w16 ; Wo -> wot16
//  2. proj MFMA: v16, qd16 (qd = q * d^i) = bf16(x16 @ w16^T + bias); epilogue
//                LDS-transposes k/v tiles -> kT16[z][d][j], vTw16[z][d][j] (gate-folded)
//  3. tail (ONE cooperative kernel, grid 256 x 512):
//       A: Ut16[z][e][d] = bf16(sum_j kT[e][j] vTw[d][j])  (one 128x128 quadrant/block)
//       -- grid.sync --
//       B: scan -> T16[z] = bf16(S_c^T), final_state
//       -- grid.sync --
//       C: chunk_attn: A = mask(qd@v^T) -> LDS swizzled; mo16 = qd@T^T + A@kT^T
//  4. y MFMA:    out_y = mo16 @ wot16^T + bo

namespace cg = cooperative_groups;

using bf16x8 = __attribute__((ext_vector_type(8))) short;
using f32x4  = __attribute__((ext_vector_type(4))) float;
using u16x4  = __attribute__((ext_vector_type(4))) unsigned short;
using u16x8  = __attribute__((ext_vector_type(8))) unsigned short;

__device__ inline unsigned short f2bf(float f) {
  unsigned int u = __float_as_uint(f);
  u = (u + 0x7FFF + ((u >> 16) & 1)) >> 16;
  return (unsigned short)u;
}
__device__ inline float bf2f(unsigned short u) {
  return __uint_as_float(((unsigned int)u) << 16);
}

#define GLD_LDS(gsrc, ldst) \
  __builtin_amdgcn_global_load_lds( \
      (const __attribute__((address_space(1))) unsigned int*)(gsrc), \
      (__attribute__((address_space(3))) unsigned int*)(ldst), 16, 0, 0)

// ---------------------------------------------------------------- MFMA GEMM
// C = A[M][K] * B[N][K]^T, 128x128 tile, BK=64, 4 waves, global_load_lds staging.
struct MP {
  const unsigned short* A; long long a_bs; int lda;
  const unsigned short* B; long long b_bs; int ldb;
  int K, grid_n;
  int swz;                                    // 1: XCD-chunked blockIdx swizzle
  float* Cf; unsigned short* Cb; long long c_bs; int ldc;
  const float* bias0; const float* bias1; const float* bias2;
  const float* decay_ptr;
  const float* gate;
  unsigned short* o_v; unsigned short* o_qd;
  unsigned short* o_kT; unsigned short* o_vTw;
};

// EPI: 0=proj (v16/qd16 + transposed kT16/vTw16), 1=f32+bias (y)
template<int EPI>
__global__ __launch_bounds__(256)
void gemm_mfma(MP p) {
  __shared__ unsigned short smem[2 * 128 * 64];   // As | Bs ; reused as 128x128 trans buf
  __shared__ float warr[128];
  unsigned short* As = smem;
  unsigned short* Bs = smem + 128 * 64;
  const int tid = threadIdx.x;
  const int bid = p.swz ? ((blockIdx.x & 7) * (gridDim.x >> 3) + (blockIdx.x >> 3))
                        : blockIdx.x;
  const int bn = bid % p.grid_n, bm = bid / p.grid_n;
  const int m0 = bm * 128, n0 = bn * 128;
  const int lane = tid & 63, wv = tid >> 6;
  const int wr = wv >> 1, wc = wv & 1;
  const int srow = tid >> 3, scol = (tid & 7) * 8;

  f32x4 acc[4][4] = {};

  const unsigned short* Abase = p.A + (long long)m0 * p.lda;
  const unsigned short* Bbase = p.B + (long long)n0 * p.ldb;

  for (int k0 = 0; k0 < p.K; k0 += 64) {
    if (k0) __syncthreads();
#pragma unroll
    for (int i = 0; i < 4; i++) {
      int row = i * 32 + srow;
      GLD_LDS(Abase + (long long)row * p.lda + k0 + scol, &As[row * 64 + scol]);
    }
#pragma unroll
    for (int i = 0; i < 4; i++) {
      int row = i * 32 + srow;
      GLD_LDS(Bbase + (long long)row * p.ldb + k0 + scol, &Bs[row * 64 + scol]);
    }
    __syncthreads();
#pragma unroll
    for (int kk = 0; kk < 2; kk++) {
      bf16x8 af[4], bfr[4];
      const int kb = kk * 32 + 8 * (lane >> 4);
#pragma unroll
      for (int m = 0; m < 4; m++)
        af[m] = *(const bf16x8*)&As[(wr * 64 + m * 16 + (lane & 15)) * 64 + kb];
#pragma unroll
      for (int n = 0; n < 4; n++)
        bfr[n] = *(const bf16x8*)&Bs[(wc * 64 + n * 16 + (lane & 15)) * 64 + kb];
#pragma unroll
      for (int m = 0; m < 4; m++)
#pragma unroll
        for (int n = 0; n < 4; n++)
          acc[m][n] = __builtin_amdgcn_mfma_f32_16x16x32_bf16(af[m], bfr[n], acc[m][n], 0, 0, 0);
    }
  }

  if (EPI == 1) {
    const int crow0 = m0 + wr * 64, ccol0 = n0 + wc * 64;
#pragma unroll
    for (int m = 0; m < 4; m++) {
#pragma unroll
      for (int n = 0; n < 4; n++) {
        int col = ccol0 + n * 16 + (lane & 15);
#pragma unroll
        for (int q = 0; q < 4; q++) {
          int row = crow0 + m * 16 + (lane >> 4) * 4 + q;
          p.Cf[(long long)row * p.ldc + col] = acc[m][n][q] + p.bias0[col];
        }
      }
    }
    return;
  }

  // ---------------- EPI 0: proj epilogue ----------------
  const float log2d = log2f(p.decay_ptr[0]);
  const int sel = bn >> 1;    // 0:k 1:v 2:q
  const int half = bn & 1;

  if (sel < 2) {
    __syncthreads();
    if (sel == 1 && tid < 128)
      warr[tid] = p.gate[(long long)bm * 128 + tid] * exp2f((float)(127 - tid) * log2d);
  }

#pragma unroll
  for (int m = 0; m < 4; m++) {
#pragma unroll
    for (int n = 0; n < 4; n++) {
      int cl = wc * 64 + n * 16 + (lane & 15);   // local col 0..127
      int d = half * 128 + cl;                   // d_mem index (for sel<2)
      float bias;
      if (sel == 0) bias = p.bias0[d];
      else if (sel == 1) bias = p.bias1[d];
      else bias = p.bias2[(n0 + cl) - 512];
      int r0 = wr * 64 + m * 16 + (lane >> 4) * 4;  // local row base
      if (sel < 2) {
        u16x4 pk;
#pragma unroll
        for (int q = 0; q < 4; q++) {
          float v = acc[m][n][q] + bias;
          pk[q] = f2bf(v);
          if (sel == 1) {
            long long row = m0 + r0 + q;
            p.o_v[row * 256 + d] = pk[q];
          }
        }
        int byteoff = (cl * 256 + r0 * 2) ^ ((cl & 7) << 4);
        *(u16x4*)((char*)smem + byteoff) = pk;
      } else {
#pragma unroll
        for (int q = 0; q < 4; q++) {
          long long row = m0 + r0 + q;
          float v = acc[m][n][q] + bias;
          p.o_qd[row * 256 + ((n0 + cl) - 512)] = f2bf(v * exp2f((float)((r0 + q) & 127) * log2d));
        }
      }
    }
  }

  if (sel < 2) {
    __syncthreads();
    unsigned short* dst = (sel == 0 ? p.o_kT : p.o_vTw) + (long long)bm * 32768;
#pragma unroll
    for (int pp = 0; pp < 8; pp++) {
      int idx = pp * 256 + tid;
      int c = idx >> 4;            // local col (d) 0..127
      int j0 = (idx & 15) * 8;     // row-run start
      u16x8 o = *(const u16x8*)((char*)smem + ((c * 256 + j0 * 2) ^ ((c & 7) << 4)));
      if (sel == 1) {
#pragma unroll
        for (int t = 0; t < 8; t++) o[t] = f2bf(bf2f(o[t]) * warr[j0 + t]);
      }
      *(u16x8*)&dst[(long long)(half * 128 + c) * 128 + j0] = o;
    }
  }
}

// ---------------------------------------------------------------- cooperative tail
// Grid 256 blocks x 512 threads, all co-resident (1 block/CU).
// Phase A: block (z=bid>>2, eh=(bid>>1)&1, dh=bid&1) computes Ut quadrant.
// Phase B: 131072 threads x 2 scan chains.
// Phase C: block (z=bid>>2, rh=(bid>>1)&1, nh=bid&1) = chunk_attn body.
__global__ __launch_bounds__(512)
void tail_kernel(const unsigned short* __restrict__ kT16, const unsigned short* __restrict__ vTw16,
                 unsigned short* __restrict__ Ut16, const float* __restrict__ state_in,
                 unsigned short* __restrict__ T16, float* __restrict__ final_out,
                 const unsigned short* __restrict__ qd16, const unsigned short* __restrict__ v16,
                 unsigned short* __restrict__ mo16, const float* __restrict__ gbuf,
                 const float* __restrict__ decay_ptr) {
  __shared__ unsigned short pool[28672];   // 56KB
  cg::grid_group grid = cg::this_grid();
  const int tid = threadIdx.x, lane = tid & 63, wv = tid >> 6;
  const int bid = blockIdx.x;
  const int z = bid >> 2;
  const float log2d = log2f(decay_ptr[0]);

  // ================= Phase A: Ut quadrant =================
  {
    unsigned short* As = pool;              // 128x64
    unsigned short* Bs = pool + 8192;       // 128x64
    const int eh = (bid >> 1) & 1, dh = bid & 1;
    const int e0 = eh * 128, d0 = dh * 128;
    const int wr = wv >> 2, wc = wv & 3;    // 2 x 4 waves over 128x128
    const int srow = tid >> 3, scol = (tid & 7) * 8;   // srow 0..63
    const unsigned short* kz = kT16 + (long long)z * 32768;
    const unsigned short* vz = vTw16 + (long long)z * 32768;
    f32x4 acc[4][2] = {};
    for (int k0 = 0; k0 < 128; k0 += 64) {
      if (k0) __syncthreads();
#pragma unroll
      for (int i = 0; i < 2; i++) {
        int row = i * 64 + srow;
        GLD_LDS(kz + (long long)(e0 + row) * 128 + k0 + scol, &As[row * 64 + scol]);
        GLD_LDS(vz + (long long)(d0 + row) * 128 + k0 + scol, &Bs[row * 64 + scol]);
      }
      __syncthreads();
#pragma unroll
      for (int kk = 0; kk < 2; kk++) {
        const int kb = kk * 32 + 8 * (lane >> 4);
        bf16x8 af[4], bfr[2];
#pragma unroll
        for (int m = 0; m < 4; m++)
          af[m] = *(const bf16x8*)&As[(wr * 64 + m * 16 + (lane & 15)) * 64 + kb];
#pragma unroll
        for (int n = 0; n < 2; n++)
          bfr[n] = *(const bf16x8*)&Bs[(wc * 32 + n * 16 + (lane & 15)) * 64 + kb];
#pragma unroll
        for (int m = 0; m < 4; m++)
#pragma unroll
          for (int n = 0; n < 2; n++)
            acc[m][n] = __builtin_amdgcn_mfma_f32_16x16x32_bf16(af[m], bfr[n], acc[m][n], 0, 0, 0);
      }
    }
#pragma unroll
    for (int m = 0; m < 4; m++) {
#pragma unroll
      for (int n = 0; n < 2; n++) {
        int col = d0 + wc * 32 + n * 16 + (lane & 15);
#pragma unroll
        for (int q = 0; q < 4; q++) {
          int row = e0 + wr * 64 + m * 16 + (lane >> 4) * 4 + q;
          Ut16[(long long)z * 65536 + (long long)row * 256 + col] = f2bf(acc[m][n][q]);
        }
      }
    }
  }

  __threadfence();
  grid.sync();

  // ================= Phase B: chunk-state scan =================
  {
    float dC = exp2f(128.f * log2d);
    int t0 = bid * 512 + tid;                 // 0..131071
#pragma unroll
    for (int h = 0; h < 2; h++) {
      int t = t0 + h * 131072;                // 0..262143
      int b = t >> 16, pidx = t & 65535;      // pidx = e*256+d
      int e = pidx >> 8, d = pidx & 255;
      float cur = state_in[(long long)b * 65536 + d * 256 + e];
#pragma unroll
      for (int c = 0; c < 16; c++) {
        long long off = ((long long)(b * 16 + c)) * 65536 + pidx;
        T16[off] = f2bf(cur);
        cur = fmaf(dC, cur, bf2f(Ut16[off]));
      }
      final_out[(long long)b * 65536 + d * 256 + e] = cur;
    }
  }

  __threadfence();
  grid.sync();

  // ================= Phase C: fused chunk attention =================
  {
    unsigned short* As = pool;                // qd rows (64x64, 8KB)
    unsigned short* Bs = pool + 4096;         // v | T (2x128x64, 32KB); reused for kT
    unsigned short* Al = pool + 4096 + 16384; // swizzled scores (64x128, 16KB)
    const int nh = bid & 1, rh = (bid >> 1) & 1;
    const int roff = rh * 64;
    const int wr = wv >> 2, wc = wv & 3;      // 2 x 4 wave grid
    const int srow = tid >> 3, scol = (tid & 7) * 8;

    const unsigned short* qz = qd16 + (long long)z * 32768 + (long long)roff * 256;
    const unsigned short* vz = v16 + (long long)z * 32768;
    const unsigned short* Tz = T16 + (long long)z * 65536 + (long long)nh * 128 * 256;
    const unsigned short* kz = kT16 + (long long)z * 32768 + (long long)nh * 128 * 128;

    f32x4 acc1[2][2] = {};
    f32x4 acc2[2][2] = {};

    __syncthreads();   // pool reuse safe across phases

    // ---- fused phase 1 (scores) + phase 2a (qd@T^T), K=256 ----
    for (int k0 = 0; k0 < 256; k0 += 64) {
      if (k0) __syncthreads();
      GLD_LDS(qz + (long long)srow * 256 + k0 + scol, &As[srow * 64 + scol]);
#pragma unroll
      for (int i = 0; i < 2; i++) {
        int row = i * 64 + srow;
        GLD_LDS(vz + (long long)row * 256 + k0 + scol, &Bs[row * 64 + scol]);
        GLD_LDS(Tz + (long long)row * 256 + k0 + scol, &Bs[8192 + row * 64 + scol]);
      }
      __syncthreads();
#pragma unroll
      for (int kk = 0; kk < 2; kk++) {
        const int kb = kk * 32 + 8 * (lane >> 4);
        bf16x8 af[2], bv[2], bt[2];
#pragma unroll
        for (int m = 0; m < 2; m++)
          af[m] = *(const bf16x8*)&As[(wr * 32 + m * 16 + (lane & 15)) * 64 + kb];
#pragma unroll
        for (int n = 0; n < 2; n++) {
          bv[n] = *(const bf16x8*)&Bs[(wc * 32 + n * 16 + (lane & 15)) * 64 + kb];
          bt[n] = *(const bf16x8*)&Bs[8192 + (wc * 32 + n * 16 + (lane & 15)) * 64 + kb];
        }
#pragma unroll
        for (int m = 0; m < 2; m++)
#pragma unroll
          for (int n = 0; n < 2; n++) {
            acc1[m][n] = __builtin_amdgcn_mfma_f32_16x16x32_bf16(af[m], bv[n], acc1[m][n], 0, 0, 0);
            acc2[m][n] = __builtin_amdgcn_mfma_f32_16x16x32_bf16(af[m], bt[n], acc2[m][n], 0, 0, 0);
          }
      }
    }

    // ---- scores epilogue -> Al (mask, gate-scale, bf16, swizzled) ----
#pragma unroll
    for (int n = 0; n < 2; n++) {
      int col = wc * 32 + n * 16 + (lane & 15);   // j in [0,128)
      float gsc = gbuf[z * 128 + col] * exp2f(-(float)(col + 1) * log2d);
#pragma unroll
      for (int m = 0; m < 2; m++) {
#pragma unroll
        for (int q = 0; q < 4; q++) {
          int r = wr * 32 + m * 16 + (lane >> 4) * 4 + q;   // local row
          float v = (col < roff + r) ? acc1[m][n][q] * gsc : 0.f;
          int byteoff = (r * 256 + col * 2) ^ ((r & 7) << 4);
          *(unsigned short*)((char*)Al + byteoff) = f2bf(v);
        }
      }
    }
    __syncthreads();   // Al visible; all waves done with Bs

    // ---- phase 2b: acc2 += A @ kT^T, K=128 ----
    for (int k0 = 0; k0 < 128; k0 += 64) {
      if (k0) __syncthreads();
#pragma unroll
      for (int i = 0; i < 2; i++) {
        int row = i * 64 + srow;
        GLD_LDS(kz + (long long)row * 128 + k0 + scol, &Bs[row * 64 + scol]);
      }
      __syncthreads();
#pragma unroll
      for (int kk = 0; kk < 2; kk++) {
        const int kbb = k0 + kk * 32 + 8 * (lane >> 4);
        bf16x8 af[2], bk_[2];
#pragma unroll
        for (int m = 0; m < 2; m++) {
          int r = wr * 32 + m * 16 + (lane & 15);
          af[m] = *(const bf16x8*)((char*)Al + ((r * 256 + kbb * 2) ^ ((r & 7) << 4)));
        }
#pragma unroll
        for (int n = 0; n < 2; n++)
          bk_[n] = *(const bf16x8*)&Bs[(wc * 32 + n * 16 + (lane & 15)) * 64 + kk * 32 + 8 * (lane >> 4)];
#pragma unroll
        for (int m = 0; m < 2; m++)
#pragma unroll
          for (int n = 0; n < 2; n++)
            acc2[m][n] = __builtin_amdgcn_mfma_f32_16x16x32_bf16(af[m], bk_[n], acc2[m][n], 0, 0, 0);
      }
    }

    // ---- store mo ----
#pragma unroll
    for (int m = 0; m < 2; m++) {
#pragma unroll
      for (int n = 0; n < 2; n++) {
        int col = nh * 128 + wc * 32 + n * 16 + (lane & 15);
#pragma unroll
        for (int q = 0; q < 4; q++) {
          int row = roff + wr * 32 + m * 16 + (lane >> 4) * 4 + q;
          mo16[((long long)z * 128 + row) * 256 + col] = f2bf(acc2[m][n][q]);
        }
      }
    }
  }
}

// ---------------------------------------------------------------- prep (cast+gate+weight transposes)
__global__ __launch_bounds__(256)
void prep_kernel(const float* __restrict__ x, const float* __restrict__ Wg,
                 const float* __restrict__ bg, unsigned short* __restrict__ x16,
                 float* __restrict__ g,
                 const float* __restrict__ Wk, const float* __restrict__ Wv,
                 const float* __restrict__ Wq, unsigned short* __restrict__ w16,
                 const float* __restrict__ Wo, unsigned short* __restrict__ wot16) {
  __shared__ float tile[64][65];
  const int bx = blockIdx.x;
  const int tid = threadIdx.x;
  if (bx < 2048) {
    const int wave = tid >> 6, lane = tid & 63;
    const long long row = (long long)bx * 4 + wave;
    const float* xr = x + row * 1024 + lane * 16;
    const float* wr = Wg + lane * 16;
    float s = 0.f;
    u16x8 o0, o1;
#pragma unroll
    for (int qq = 0; qq < 2; qq++) {
      float4 a = *(const float4*)(xr + qq * 4);
      float4 w = *(const float4*)(wr + qq * 4);
      s = fmaf(a.x, w.x, s); s = fmaf(a.y, w.y, s);
      s = fmaf(a.z, w.z, s); s = fmaf(a.w, w.w, s);
      o0[qq * 4 + 0] = f2bf(a.x); o0[qq * 4 + 1] = f2bf(a.y);
      o0[qq * 4 + 2] = f2bf(a.z); o0[qq * 4 + 3] = f2bf(a.w);
    }
#pragma unroll
    for (int qq = 0; qq < 2; qq++) {
      float4 a = *(const float4*)(xr + 8 + qq * 4);
      float4 w = *(const float4*)(wr + 8 + qq * 4);
      s = fmaf(a.x, w.x, s); s = fmaf(a.y, w.y, s);
      s = fmaf(a.z, w.z, s); s = fmaf(a.w, w.w, s);
      o1[qq * 4 + 0] = f2bf(a.x); o1[qq * 4 + 1] = f2bf(a.y);
      o1[qq * 4 + 2] = f2bf(a.z); o1[qq * 4 + 3] = f2bf(a.w);
    }
    *(u16x8*)(x16 + row * 1024 + lane * 16) = o0;
    *(u16x8*)(x16 + row * 1024 + lane * 16 + 8) = o1;
#pragma unroll
    for (int off = 32; off; off >>= 1) s += __shfl_xor(s, off, 64);
    if (lane == 0) g[row] = 1.f / (1.f + expf(-(s + bg[0])));
    return;
  }
  int t = bx - 2048;
  const float* S; unsigned short* dst;
  int srcCols, dstLd, k0, n0g, n0;
  if (t < 192) {
    k0 = (t % 16) * 64; n0g = (t / 16) * 64;
    int sel = n0g >> 8; n0 = n0g - (sel << 8);
    S = sel == 0 ? Wk : sel == 1 ? Wv : Wq;
    srcCols = 256; dst = w16; dstLd = 1024;
  } else {
    t -= 192;
    k0 = (t % 4) * 64; n0g = (t / 4) * 64; n0 = n0g;
    S = Wo; srcCols = 1024; dst = wot16; dstLd = 256;
  }
  const int rr = tid >> 4, c4 = (tid & 15) * 4;
#pragma unroll
  for (int pp = 0; pp < 4; pp++) {
    int r = pp * 16 + rr;
    float4 v = *(const float4*)&S[(long long)(k0 + r) * srcCols + n0 + c4];
    tile[r][c4 + 0] = v.x; tile[r][c4 + 1] = v.y; tile[r][c4 + 2] = v.z; tile[r][c4 + 3] = v.w;
  }
  __syncthreads();
  const int rn = tid >> 3, ck0 = (tid & 7) * 8;
#pragma unroll
  for (int pp = 0; pp < 2; pp++) {
    int n = pp * 32 + rn;
    u16x8 o;
#pragma unroll
    for (int j = 0; j < 8; j++) o[j] = f2bf(tile[ck0 + j][n]);
    *(u16x8*)&dst[(long long)(n0g + n) * dstLd + k0 + ck0] = o;
  }
}

// ---------------------------------------------------------------- launch
extern "C" void kernel_launch(void* const* d_in, const int* in_sizes, int n_in,
                              void* d_out, int out_size, void* d_ws, size_t ws_size,
                              hipStream_t stream) {
  const float* x     = (const float*)d_in[0];
  const float* state = (const float*)d_in[1];
  const float* Wk = (const float*)d_in[2];  const float* bk = (const float*)d_in[3];
  const float* Wv = (const float*)d_in[4];  const float* bv = (const float*)d_in[5];
  const float* Wq = (const float*)d_in[6];  const float* bq = (const float*)d_in[7];
  const float* Wo = (const float*)d_in[8];  const float* bo = (const float*)d_in[9];
  const float* Wg = (const float*)d_in[10]; const float* bg = (const float*)d_in[11];
  const float* decay = (const float*)d_in[12];

  float* out_y = (float*)d_out;              // [4][2048][1024]
  float* out_S = out_y + 8388608;            // [4][256][256]

  float* ws = (float*)d_ws;
  unsigned short* x16   = (unsigned short*)(ws);             // [8192][1024]
  unsigned short* v16   = (unsigned short*)(ws + 4194304);   // [8192][256]
  unsigned short* qd16  = (unsigned short*)(ws + 5242880);   // [8192][256] (q * d^i)
  unsigned short* w16   = (unsigned short*)(ws + 6291456);   // [768][1024]
  unsigned short* wot16 = (unsigned short*)(ws + 6684672);   // [1024][256]
  float*          gbuf  = ws + 6815744;                      // [8192]
  unsigned short* kT16  = (unsigned short*)(ws + 6823936);   // [64][256][128]
  unsigned short* vTw16 = (unsigned short*)(ws + 7872512);   // [64][256][128]
  unsigned short* Ut16  = (unsigned short*)(ws + 8921088);   // [64][256][256]
  unsigned short* T16   = (unsigned short*)(ws + 11018240);  // [64][256][256]
  unsigned short* mo16  = (unsigned short*)(ws + 13115392);  // [8192][256]

  // 1. prep: cast+gate + weight transposes
  prep_kernel<<<2304, 256, 0, stream>>>(x, Wg, bg, x16, gbuf, Wk, Wv, Wq, w16, Wo, wot16);

  // 2. fused projections -> v16, qd16, kT16, vTw16  (XCD-swizzled)
  {
    MP p{};
    p.A = x16; p.lda = 1024; p.B = w16; p.ldb = 1024;
    p.K = 1024; p.grid_n = 6; p.swz = 1;
    p.bias0 = bk; p.bias1 = bv; p.bias2 = bq;
    p.decay_ptr = decay; p.gate = gbuf;
    p.o_v = v16; p.o_qd = qd16; p.o_kT = kT16; p.o_vTw = vTw16;
    gemm_mfma<0><<<dim3(384, 1, 1), 256, 0, stream>>>(p);
  }

  // 3. cooperative tail: Ut + scan + chunk_attn in one kernel
  {
    const unsigned short* a_kT = kT16; const unsigned short* a_vTw = vTw16;
    unsigned short* a_Ut = Ut16; const float* a_state = state;
    unsigned short* a_T = T16; float* a_final = out_S;
    const unsigned short* a_qd = qd16; const unsigned short* a_v = v16;
    unsigned short* a_mo = mo16; const float* a_g = gbuf; const float* a_d = decay;
    void* kargs[] = {&a_kT, &a_vTw, &a_Ut, &a_state, &a_T, &a_final,
                     &a_qd, &a_v, &a_mo, &a_g, &a_d};
    hipLaunchCooperativeKernel((void*)tail_kernel, dim3(256, 1, 1), dim3(512, 1, 1),
                               kargs, 0, stream);
  }

  // 4. y = mo16 @ wot16^T + bo  (XCD-swizzled)
  {
    MP p{};
    p.A = mo16; p.lda = 256;
    p.B = wot16; p.ldb = 256;
    p.K = 256; p.grid_n = 8; p.swz = 1;
    p.Cf = out_y; p.ldc = 1024;
    p.bias0 = bo; p.decay_ptr = decay;
    gemm_mfma<1><<<dim3(512, 1, 1), 256, 0, stream>>>(p);
  }
}

// Round 9
// 86.866 us; speedup vs baseline: 3.4781x; 3.4781x over previous
//
#include <hip/hip_runtime.h>
#include <math.h>

// NeuralMemory: chunked-parallel decaying rank-1 memory scan, all-MFMA version.
//   S_t = decay*S_{t-1} + s_t * v_t k_t^T ;  out_t = q_t^T S_{t-1}
// Chunk C=128, NC=16, b=4, s=2048, d_model=1024, d_mem=256.
//
//  1. prep:      x -> x16 ; gate = sigmoid(x@Wg+bg) ; Wk|Wv|Wq -> w16 ; Wo -> wot16
//  2. proj:      64x128-tile MFMA (768 blocks, 3/CU): v16, qd16 = bf16(x16@w16^T + b);
//                epilogue LDS-transposes k/v half-tiles -> kT16/vTw16 (gate-folded)
//  3. Ut MFMA:   Ut16[z][e][d] = bf16(sum_j kT[e][j] vTw[d][j])   (= U_c^T)
//  4. scan:      T16[z] = bf16(S_c^T) running over chunks; writes final_state
//  5. chunk_attn (per nh,rh,z): A(64x128) = mask(qd@v^T) -> LDS swizzled;
//                mo16 = qd@T^T + A@kT^T    (p1/p2a fused)
//  6. y MFMA:    out_y = mo16 @ wot16^T + bo   [XCD-swizzled grid]

using bf16x8 = __attribute__((ext_vector_type(8))) short;
using f32x4  = __attribute__((ext_vector_type(4))) float;
using u16x4  = __attribute__((ext_vector_type(4))) unsigned short;
using u16x8  = __attribute__((ext_vector_type(8))) unsigned short;

__device__ inline unsigned short f2bf(float f) {
  unsigned int u = __float_as_uint(f);
  u = (u + 0x7FFF + ((u >> 16) & 1)) >> 16;
  return (unsigned short)u;
}
__device__ inline float bf2f(unsigned short u) {
  return __uint_as_float(((unsigned int)u) << 16);
}

#define GLD_LDS(gsrc, ldst) \
  __builtin_amdgcn_global_load_lds( \
      (const __attribute__((address_space(1))) unsigned int*)(gsrc), \
      (__attribute__((address_space(3))) unsigned int*)(ldst), 16, 0, 0)

// ---------------------------------------------------------------- generic MFMA GEMM
// C = A[M][K] * B[N][K]^T, 128x128 tile, BK=64, 4 waves, global_load_lds staging.
struct MP {
  const unsigned short* A; long long a_bs; int lda;
  const unsigned short* B; long long b_bs; int ldb;
  int K, grid_n;
  int swz;                                    // 1: XCD-chunked blockIdx swizzle
  float* Cf; unsigned short* Cb; long long c_bs; int ldc;
  const float* bias0;
};

// EPI: 1=f32+bias (y), 4=bf16 batched (Ut)
template<int EPI>
__global__ __launch_bounds__(256)
void gemm_mfma(MP p) {
  __shared__ unsigned short As[128 * 64];
  __shared__ unsigned short Bs[128 * 64];
  const int tid = threadIdx.x;
  const int bid = p.swz ? ((blockIdx.x & 7) * (gridDim.x >> 3) + (blockIdx.x >> 3))
                        : blockIdx.x;
  const int bn = bid % p.grid_n, bm = bid / p.grid_n;
  const int m0 = bm * 128, n0 = bn * 128;
  const long long z = blockIdx.z;
  const int lane = tid & 63, wv = tid >> 6;
  const int wr = wv >> 1, wc = wv & 1;
  const int srow = tid >> 3, scol = (tid & 7) * 8;

  f32x4 acc[4][4] = {};

  const unsigned short* Abase = p.A + z * p.a_bs + (long long)m0 * p.lda;
  const unsigned short* Bbase = p.B + z * p.b_bs + (long long)n0 * p.ldb;

  for (int k0 = 0; k0 < p.K; k0 += 64) {
    if (k0) __syncthreads();
#pragma unroll
    for (int i = 0; i < 4; i++) {
      int row = i * 32 + srow;
      GLD_LDS(Abase + (long long)row * p.lda + k0 + scol, &As[row * 64 + scol]);
    }
#pragma unroll
    for (int i = 0; i < 4; i++) {
      int row = i * 32 + srow;
      GLD_LDS(Bbase + (long long)row * p.ldb + k0 + scol, &Bs[row * 64 + scol]);
    }
    __syncthreads();
#pragma unroll
    for (int kk = 0; kk < 2; kk++) {
      bf16x8 af[4], bfr[4];
      const int kb = kk * 32 + 8 * (lane >> 4);
#pragma unroll
      for (int m = 0; m < 4; m++)
        af[m] = *(const bf16x8*)&As[(wr * 64 + m * 16 + (lane & 15)) * 64 + kb];
#pragma unroll
      for (int n = 0; n < 4; n++)
        bfr[n] = *(const bf16x8*)&Bs[(wc * 64 + n * 16 + (lane & 15)) * 64 + kb];
#pragma unroll
      for (int m = 0; m < 4; m++)
#pragma unroll
        for (int n = 0; n < 4; n++)
          acc[m][n] = __builtin_amdgcn_mfma_f32_16x16x32_bf16(af[m], bfr[n], acc[m][n], 0, 0, 0);
    }
  }

  const int crow0 = m0 + wr * 64, ccol0 = n0 + wc * 64;
#pragma unroll
  for (int m = 0; m < 4; m++) {
#pragma unroll
    for (int n = 0; n < 4; n++) {
      int col = ccol0 + n * 16 + (lane & 15);
#pragma unroll
      for (int q = 0; q < 4; q++) {
        int row = crow0 + m * 16 + (lane >> 4) * 4 + q;
        float v = acc[m][n][q];
        if (EPI == 1) p.Cf[(long long)row * p.ldc + col] = v + p.bias0[col];
        else          p.Cb[z * p.c_bs + (long long)row * p.ldc + col] = f2bf(v);
      }
    }
  }
}

// ---------------------------------------------------------------- proj (64x128 tile)
// Grid 768 (XCD-swizzled): bn in [0,6) selects k/v/q + 128-col half; bm in [0,128)
// is a 64-row slab (chunk z = bm>>1, j-half = bm&1). 4 waves, wave cols wv*32..+32.
__global__ __launch_bounds__(256)
void proj_kernel(const unsigned short* __restrict__ x16, const unsigned short* __restrict__ w16,
                 const float* __restrict__ bk, const float* __restrict__ bv,
                 const float* __restrict__ bq, const float* __restrict__ gate,
                 const float* __restrict__ decay_ptr,
                 unsigned short* __restrict__ o_v, unsigned short* __restrict__ o_qd,
                 unsigned short* __restrict__ o_kT, unsigned short* __restrict__ o_vTw) {
  __shared__ unsigned short As[64 * 64];    // 8KB
  __shared__ unsigned short Bs[128 * 64];   // 16KB; reused as 128x64 transpose buf
  __shared__ float warr[64];
  const int tid = threadIdx.x;
  const int bid = (blockIdx.x & 7) * (gridDim.x >> 3) + (blockIdx.x >> 3);
  const int bn = bid % 6, bm = bid / 6;
  const int m0 = bm * 64, n0 = bn * 128;
  const int lane = tid & 63, wv = tid >> 6;
  const int srow = tid >> 3, scol = (tid & 7) * 8;   // srow 0..31

  f32x4 acc[4][2] = {};
  const unsigned short* Abase = x16 + (long long)m0 * 1024;
  const unsigned short* Bbase = w16 + (long long)n0 * 1024;

  for (int k0 = 0; k0 < 1024; k0 += 64) {
    if (k0) __syncthreads();
#pragma unroll
    for (int i = 0; i < 2; i++) {
      int row = i * 32 + srow;
      GLD_LDS(Abase + (long long)row * 1024 + k0 + scol, &As[row * 64 + scol]);
    }
#pragma unroll
    for (int i = 0; i < 4; i++) {
      int row = i * 32 + srow;
      GLD_LDS(Bbase + (long long)row * 1024 + k0 + scol, &Bs[row * 64 + scol]);
    }
    __syncthreads();
#pragma unroll
    for (int kk = 0; kk < 2; kk++) {
      const int kb = kk * 32 + 8 * (lane >> 4);
      bf16x8 af[4], bfr[2];
#pragma unroll
      for (int m = 0; m < 4; m++)
        af[m] = *(const bf16x8*)&As[(m * 16 + (lane & 15)) * 64 + kb];
#pragma unroll
      for (int n = 0; n < 2; n++)
        bfr[n] = *(const bf16x8*)&Bs[(wv * 32 + n * 16 + (lane & 15)) * 64 + kb];
#pragma unroll
      for (int m = 0; m < 4; m++)
#pragma unroll
        for (int n = 0; n < 2; n++)
          acc[m][n] = __builtin_amdgcn_mfma_f32_16x16x32_bf16(af[m], bfr[n], acc[m][n], 0, 0, 0);
    }
  }

  const float log2d = log2f(decay_ptr[0]);
  const int sel = bn >> 1;        // 0:k 1:v 2:q
  const int half = bn & 1;        // 128-col half of d_mem
  const int z = bm >> 1, jbase = (bm & 1) * 64;

  if (sel < 2) {
    __syncthreads();              // all waves done with As/Bs fragments
    if (sel == 1 && tid < 64)
      warr[tid] = gate[z * 128 + jbase + tid] * exp2f((float)(127 - (jbase + tid)) * log2d);
  }

#pragma unroll
  for (int m = 0; m < 4; m++) {
#pragma unroll
    for (int n = 0; n < 2; n++) {
      int cl = wv * 32 + n * 16 + (lane & 15);   // local col 0..127
      int r0 = m * 16 + (lane >> 4) * 4;         // local row base 0..63
      float bias = (sel == 0) ? bk[half * 128 + cl]
                 : (sel == 1) ? bv[half * 128 + cl]
                 : bq[half * 128 + cl];
      if (sel < 2) {
        u16x4 pk;
#pragma unroll
        for (int q = 0; q < 4; q++) {
          float v = acc[m][n][q] + bias;
          pk[q] = f2bf(v);
          if (sel == 1)
            o_v[((long long)m0 + r0 + q) * 256 + half * 128 + cl] = pk[q];
        }
        int byteoff = (cl * 128 + r0 * 2) ^ ((cl & 7) << 4);
        *(u16x4*)((char*)Bs + byteoff) = pk;
      } else {
#pragma unroll
        for (int q = 0; q < 4; q++) {
          long long row = m0 + r0 + q;
          float v = acc[m][n][q] + bias;
          o_qd[row * 256 + half * 128 + cl] =
              f2bf(v * exp2f((float)(jbase + r0 + q) * log2d));
        }
      }
    }
  }

  if (sel < 2) {
    __syncthreads();
    unsigned short* dst = (sel == 0 ? o_kT : o_vTw) + (long long)z * 32768;
#pragma unroll
    for (int pp = 0; pp < 4; pp++) {
      int idx = pp * 256 + tid;    // 0..1023
      int c = idx >> 3;            // local col (d) 0..127
      int j0 = (idx & 7) * 8;      // row-run start 0..56
      u16x8 o = *(const u16x8*)((char*)Bs + ((c * 128 + j0 * 2) ^ ((c & 7) << 4)));
      if (sel == 1) {
#pragma unroll
        for (int t = 0; t < 8; t++) o[t] = f2bf(bf2f(o[t]) * warr[j0 + t]);
      }
      *(u16x8*)&dst[(long long)(half * 128 + c) * 128 + jbase + j0] = o;
    }
  }
}

// ---------------------------------------------------------------- fused chunk attention
__global__ __launch_bounds__(512)
void chunk_attn(const unsigned short* __restrict__ qd16, const unsigned short* __restrict__ v16,
                const unsigned short* __restrict__ kT16, const unsigned short* __restrict__ T16,
                unsigned short* __restrict__ mo16, const float* __restrict__ gbuf,
                const float* __restrict__ decay_ptr) {
  __shared__ unsigned short As[64 * 64];        // qd rows (8KB)
  __shared__ unsigned short Bs[2 * 128 * 64];   // v | T (32KB); reused for kT
  __shared__ unsigned short Al[64 * 128];       // swizzled scores (16KB)
  const int tid = threadIdx.x, lane = tid & 63, wv = tid >> 6;
  const int wr = wv >> 2, wc = wv & 3;          // 2 x 4 wave grid
  const int nh = blockIdx.x, rh = blockIdx.y, z = blockIdx.z;
  const int roff = rh * 64;
  const int srow = tid >> 3, scol = (tid & 7) * 8;
  const float log2d = log2f(decay_ptr[0]);

  const unsigned short* qz = qd16 + (long long)z * 32768 + (long long)roff * 256;
  const unsigned short* vz = v16 + (long long)z * 32768;
  const unsigned short* Tz = T16 + (long long)z * 65536 + (long long)nh * 128 * 256;
  const unsigned short* kz = kT16 + (long long)z * 32768 + (long long)nh * 128 * 128;

  f32x4 acc1[2][2] = {};
  f32x4 acc2[2][2] = {};

  // ---- fused phase 1 (scores) + phase 2a (qd@T^T), K=256 ----
  for (int k0 = 0; k0 < 256; k0 += 64) {
    if (k0) __syncthreads();
    GLD_LDS(qz + (long long)srow * 256 + k0 + scol, &As[srow * 64 + scol]);
#pragma unroll
    for (int i = 0; i < 2; i++) {
      int row = i * 64 + srow;
      GLD_LDS(vz + (long long)row * 256 + k0 + scol, &Bs[row * 64 + scol]);
      GLD_LDS(Tz + (long long)row * 256 + k0 + scol, &Bs[8192 + row * 64 + scol]);
    }
    __syncthreads();
#pragma unroll
    for (int kk = 0; kk < 2; kk++) {
      const int kb = kk * 32 + 8 * (lane >> 4);
      bf16x8 af[2], bv[2], bt[2];
#pragma unroll
      for (int m = 0; m < 2; m++)
        af[m] = *(const bf16x8*)&As[(wr * 32 + m * 16 + (lane & 15)) * 64 + kb];
#pragma unroll
      for (int n = 0; n < 2; n++) {
        bv[n] = *(const bf16x8*)&Bs[(wc * 32 + n * 16 + (lane & 15)) * 64 + kb];
        bt[n] = *(const bf16x8*)&Bs[8192 + (wc * 32 + n * 16 + (lane & 15)) * 64 + kb];
      }
#pragma unroll
      for (int m = 0; m < 2; m++)
#pragma unroll
        for (int n = 0; n < 2; n++) {
          acc1[m][n] = __builtin_amdgcn_mfma_f32_16x16x32_bf16(af[m], bv[n], acc1[m][n], 0, 0, 0);
          acc2[m][n] = __builtin_amdgcn_mfma_f32_16x16x32_bf16(af[m], bt[n], acc2[m][n], 0, 0, 0);
        }
    }
  }

  // ---- scores epilogue -> Al (mask, gate-scale, bf16, swizzled) ----
#pragma unroll
  for (int n = 0; n < 2; n++) {
    int col = wc * 32 + n * 16 + (lane & 15);   // j in [0,128)
    float gsc = gbuf[z * 128 + col] * exp2f(-(float)(col + 1) * log2d);
#pragma unroll
    for (int m = 0; m < 2; m++) {
#pragma unroll
      for (int q = 0; q < 4; q++) {
        int r = wr * 32 + m * 16 + (lane >> 4) * 4 + q;   // local row
        float v = (col < roff + r) ? acc1[m][n][q] * gsc : 0.f;
        int byteoff = (r * 256 + col * 2) ^ ((r & 7) << 4);
        *(unsigned short*)((char*)Al + byteoff) = f2bf(v);
      }
    }
  }
  __syncthreads();   // Al visible; all waves done with Bs

  // ---- phase 2b: acc2 += A @ kT^T, K=128 ----
  for (int k0 = 0; k0 < 128; k0 += 64) {
    if (k0) __syncthreads();
#pragma unroll
    for (int i = 0; i < 2; i++) {
      int row = i * 64 + srow;
      GLD_LDS(kz + (long long)row * 128 + k0 + scol, &Bs[row * 64 + scol]);
    }
    __syncthreads();
#pragma unroll
    for (int kk = 0; kk < 2; kk++) {
      const int kbb = k0 + kk * 32 + 8 * (lane >> 4);
      bf16x8 af[2], bk_[2];
#pragma unroll
      for (int m = 0; m < 2; m++) {
        int r = wr * 32 + m * 16 + (lane & 15);
        af[m] = *(const bf16x8*)((char*)Al + ((r * 256 + kbb * 2) ^ ((r & 7) << 4)));
      }
#pragma unroll
      for (int n = 0; n < 2; n++)
        bk_[n] = *(const bf16x8*)&Bs[(wc * 32 + n * 16 + (lane & 15)) * 64 + kk * 32 + 8 * (lane >> 4)];
#pragma unroll
      for (int m = 0; m < 2; m++)
#pragma unroll
        for (int n = 0; n < 2; n++)
          acc2[m][n] = __builtin_amdgcn_mfma_f32_16x16x32_bf16(af[m], bk_[n], acc2[m][n], 0, 0, 0);
    }
  }

  // ---- store mo ----
#pragma unroll
  for (int m = 0; m < 2; m++) {
#pragma unroll
    for (int n = 0; n < 2; n++) {
      int col = nh * 128 + wc * 32 + n * 16 + (lane & 15);
#pragma unroll
      for (int q = 0; q < 4; q++) {
        int row = roff + wr * 32 + m * 16 + (lane >> 4) * 4 + q;
        mo16[((long long)z * 128 + row) * 256 + col] = f2bf(acc2[m][n][q]);
      }
    }
  }
}

// ---------------------------------------------------------------- prep (cast+gate+weight transposes)
__global__ __launch_bounds__(256)
void prep_kernel(const float* __restrict__ x, const float* __restrict__ Wg,
                 const float* __restrict__ bg, unsigned short* __restrict__ x16,
                 float* __restrict__ g,
                 const float* __restrict__ Wk, const float* __restrict__ Wv,
                 const float* __restrict__ Wq, unsigned short* __restrict__ w16,
                 const float* __restrict__ Wo, unsigned short* __restrict__ wot16) {
  __shared__ float tile[64][65];
  const int bx = blockIdx.x;
  const int tid = threadIdx.x;
  if (bx < 2048) {
    const int wave = tid >> 6, lane = tid & 63;
    const long long row = (long long)bx * 4 + wave;
    const float* xr = x + row * 1024 + lane * 16;
    const float* wr = Wg + lane * 16;
    float s = 0.f;
    u16x8 o0, o1;
#pragma unroll
    for (int qq = 0; qq < 2; qq++) {
      float4 a = *(const float4*)(xr + qq * 4);
      float4 w = *(const float4*)(wr + qq * 4);
      s = fmaf(a.x, w.x, s); s = fmaf(a.y, w.y, s);
      s = fmaf(a.z, w.z, s); s = fmaf(a.w, w.w, s);
      o0[qq * 4 + 0] = f2bf(a.x); o0[qq * 4 + 1] = f2bf(a.y);
      o0[qq * 4 + 2] = f2bf(a.z); o0[qq * 4 + 3] = f2bf(a.w);
    }
#pragma unroll
    for (int qq = 0; qq < 2; qq++) {
      float4 a = *(const float4*)(xr + 8 + qq * 4);
      float4 w = *(const float4*)(wr + 8 + qq * 4);
      s = fmaf(a.x, w.x, s); s = fmaf(a.y, w.y, s);
      s = fmaf(a.z, w.z, s); s = fmaf(a.w, w.w, s);
      o1[qq * 4 + 0] = f2bf(a.x); o1[qq * 4 + 1] = f2bf(a.y);
      o1[qq * 4 + 2] = f2bf(a.z); o1[qq * 4 + 3] = f2bf(a.w);
    }
    *(u16x8*)(x16 + row * 1024 + lane * 16) = o0;
    *(u16x8*)(x16 + row * 1024 + lane * 16 + 8) = o1;
#pragma unroll
    for (int off = 32; off; off >>= 1) s += __shfl_xor(s, off, 64);
    if (lane == 0) g[row] = 1.f / (1.f + expf(-(s + bg[0])));
    return;
  }
  int t = bx - 2048;
  const float* S; unsigned short* dst;
  int srcCols, dstLd, k0, n0g, n0;
  if (t < 192) {
    k0 = (t % 16) * 64; n0g = (t / 16) * 64;
    int sel = n0g >> 8; n0 = n0g - (sel << 8);
    S = sel == 0 ? Wk : sel == 1 ? Wv : Wq;
    srcCols = 256; dst = w16; dstLd = 1024;
  } else {
    t -= 192;
    k0 = (t % 4) * 64; n0g = (t / 4) * 64; n0 = n0g;
    S = Wo; srcCols = 1024; dst = wot16; dstLd = 256;
  }
  const int rr = tid >> 4, c4 = (tid & 15) * 4;
#pragma unroll
  for (int pp = 0; pp < 4; pp++) {
    int r = pp * 16 + rr;
    float4 v = *(const float4*)&S[(long long)(k0 + r) * srcCols + n0 + c4];
    tile[r][c4 + 0] = v.x; tile[r][c4 + 1] = v.y; tile[r][c4 + 2] = v.z; tile[r][c4 + 3] = v.w;
  }
  __syncthreads();
  const int rn = tid >> 3, ck0 = (tid & 7) * 8;
#pragma unroll
  for (int pp = 0; pp < 2; pp++) {
    int n = pp * 32 + rn;
    u16x8 o;
#pragma unroll
    for (int j = 0; j < 8; j++) o[j] = f2bf(tile[ck0 + j][n]);
    *(u16x8*)&dst[(long long)(n0g + n) * dstLd + k0 + ck0] = o;
  }
}

// ---------------------------------------------------------------- chunk-state scan
__global__ __launch_bounds__(256)
void scan_kernel(const unsigned short* __restrict__ Ut16, const float* __restrict__ state_in,
                 unsigned short* __restrict__ T16, float* __restrict__ final_out,
                 const float* __restrict__ decay_ptr) {
  int t = blockIdx.x * 256 + threadIdx.x;   // 0..262143
  int b = t >> 16, pidx = t & 65535;        // pidx = e*256+d
  int e = pidx >> 8, d = pidx & 255;
  float dC = exp2f(128.f * log2f(decay_ptr[0]));
  float cur = state_in[(long long)b * 65536 + d * 256 + e];
#pragma unroll
  for (int c = 0; c < 16; c++) {
    long long off = ((long long)(b * 16 + c)) * 65536 + pidx;
    T16[off] = f2bf(cur);
    cur = fmaf(dC, cur, bf2f(Ut16[off]));
  }
  final_out[(long long)b * 65536 + d * 256 + e] = cur;
}

// ---------------------------------------------------------------- launch
extern "C" void kernel_launch(void* const* d_in, const int* in_sizes, int n_in,
                              void* d_out, int out_size, void* d_ws, size_t ws_size,
                              hipStream_t stream) {
  const float* x     = (const float*)d_in[0];
  const float* state = (const float*)d_in[1];
  const float* Wk = (const float*)d_in[2];  const float* bk = (const float*)d_in[3];
  const float* Wv = (const float*)d_in[4];  const float* bv = (const float*)d_in[5];
  const float* Wq = (const float*)d_in[6];  const float* bq = (const float*)d_in[7];
  const float* Wo = (const float*)d_in[8];  const float* bo = (const float*)d_in[9];
  const float* Wg = (const float*)d_in[10]; const float* bg = (const float*)d_in[11];
  const float* decay = (const float*)d_in[12];

  float* out_y = (float*)d_out;              // [4][2048][1024]
  float* out_S = out_y + 8388608;            // [4][256][256]

  float* ws = (float*)d_ws;
  unsigned short* x16   = (unsigned short*)(ws);             // [8192][1024]
  unsigned short* v16   = (unsigned short*)(ws + 4194304);   // [8192][256]
  unsigned short* qd16  = (unsigned short*)(ws + 5242880);   // [8192][256] (q * d^i)
  unsigned short* w16   = (unsigned short*)(ws + 6291456);   // [768][1024]
  unsigned short* wot16 = (unsigned short*)(ws + 6684672);   // [1024][256]
  float*          gbuf  = ws + 6815744;                      // [8192]
  unsigned short* kT16  = (unsigned short*)(ws + 6823936);   // [64][256][128]
  unsigned short* vTw16 = (unsigned short*)(ws + 7872512);   // [64][256][128]
  unsigned short* Ut16  = (unsigned short*)(ws + 8921088);   // [64][256][256]
  unsigned short* T16   = (unsigned short*)(ws + 11018240);  // [64][256][256]
  unsigned short* mo16  = (unsigned short*)(ws + 13115392);  // [8192][256]

  // 1. prep: cast+gate + weight transposes
  prep_kernel<<<2304, 256, 0, stream>>>(x, Wg, bg, x16, gbuf, Wk, Wv, Wq, w16, Wo, wot16);

  // 2. proj (64x128 tiles, 768 blocks, XCD-swizzled) -> v16, qd16, kT16, vTw16
  proj_kernel<<<768, 256, 0, stream>>>(x16, w16, bk, bv, bq, gbuf, decay,
                                       v16, qd16, kT16, vTw16);

  // 3. Ut[z] = kT @ vTw^T -> bf16
  {
    MP p{};
    p.A = kT16;  p.a_bs = 32768; p.lda = 128;
    p.B = vTw16; p.b_bs = 32768; p.ldb = 128;
    p.K = 128; p.grid_n = 2; p.swz = 0;
    p.Cb = Ut16; p.c_bs = 65536; p.ldc = 256;
    gemm_mfma<4><<<dim3(4, 1, 64), 256, 0, stream>>>(p);
  }

  // 4. chunk-state scan -> T16 + final_state
  scan_kernel<<<1024, 256, 0, stream>>>(Ut16, state, T16, out_S, decay);

  // 5. fused scores + mem_out
  chunk_attn<<<dim3(2, 2, 64), 512, 0, stream>>>(qd16, v16, kT16, T16, mo16, gbuf, decay);

  // 6. y = mo16 @ wot16^T + bo  (XCD-swizzled)
  {
    MP p{};
    p.A = mo16; p.lda = 256;
    p.B = wot16; p.ldb = 256;
    p.K = 256; p.grid_n = 8; p.swz = 1;
    p.Cf = out_y; p.ldc = 1024;
    p.bias0 = bo;
    gemm_mfma<1><<<dim3(512, 1, 1), 256, 0, stream>>>(p);
  }
}

// Round 10
// 80.560 us; speedup vs baseline: 3.7504x; 1.0783x over previous
//
#include <hip/hip_runtime.h>
#include <math.h>

// NeuralMemory: chunked-parallel decaying rank-1 memory scan, all-MFMA version.
//   S_t = decay*S_{t-1} + s_t * v_t k_t^T ;  out_t = q_t^T S_{t-1}
// Chunk C=128, NC=16, b=4, s=2048, d_model=1024, d_mem=256.
//
//  1. prep:      x -> x16 ; gate = sigmoid(x@Wg+bg) ; Wk|Wv|Wq -> w16 ; Wo -> wot16
//  2. proj:      64x128-tile MFMA (768 blocks, 3/CU): v16, qd16 = bf16(x16@w16^T + b);
//                epilogue LDS-transposes k/v half-tiles -> kT16/vTw16 (gate-folded)
//  3. Ut MFMA:   Ut16[z][e][d] = bf16(sum_j kT[e][j] vTw[d][j])   (= U_c^T)
//  4. scan:      T16[z] = bf16(S_c^T) running over chunks; writes final_state
//  5. chunk_attn (per nh,rh,z): A(64x128) = mask(qd@v^T) -> LDS swizzled;
//                mo16 = qd@T^T + A@kT^T    (p1/p2a fused)
//  6. y64:       64x128-tile MFMA (1024 blocks, 4/CU): out_y = mo16 @ wot16^T + bo

using bf16x8 = __attribute__((ext_vector_type(8))) short;
using f32x4  = __attribute__((ext_vector_type(4))) float;
using u16x4  = __attribute__((ext_vector_type(4))) unsigned short;
using u16x8  = __attribute__((ext_vector_type(8))) unsigned short;

__device__ inline unsigned short f2bf(float f) {
  unsigned int u = __float_as_uint(f);
  u = (u + 0x7FFF + ((u >> 16) & 1)) >> 16;
  return (unsigned short)u;
}
__device__ inline float bf2f(unsigned short u) {
  return __uint_as_float(((unsigned int)u) << 16);
}

#define GLD_LDS(gsrc, ldst) \
  __builtin_amdgcn_global_load_lds( \
      (const __attribute__((address_space(1))) unsigned int*)(gsrc), \
      (__attribute__((address_space(3))) unsigned int*)(ldst), 16, 0, 0)

// ---------------------------------------------------------------- Ut MFMA GEMM
// C = A[M][K] * B[N][K]^T, 128x128 tile, BK=64, 4 waves, global_load_lds staging.
struct MP {
  const unsigned short* A; long long a_bs; int lda;
  const unsigned short* B; long long b_bs; int ldb;
  int K, grid_n;
  unsigned short* Cb; long long c_bs; int ldc;
};

__global__ __launch_bounds__(256)
void gemm_ut(MP p) {
  __shared__ unsigned short As[128 * 64];
  __shared__ unsigned short Bs[128 * 64];
  const int tid = threadIdx.x;
  const int bid = blockIdx.x;
  const int bn = bid % p.grid_n, bm = bid / p.grid_n;
  const int m0 = bm * 128, n0 = bn * 128;
  const long long z = blockIdx.z;
  const int lane = tid & 63, wv = tid >> 6;
  const int wr = wv >> 1, wc = wv & 1;
  const int srow = tid >> 3, scol = (tid & 7) * 8;

  f32x4 acc[4][4] = {};

  const unsigned short* Abase = p.A + z * p.a_bs + (long long)m0 * p.lda;
  const unsigned short* Bbase = p.B + z * p.b_bs + (long long)n0 * p.ldb;

  for (int k0 = 0; k0 < p.K; k0 += 64) {
    if (k0) __syncthreads();
#pragma unroll
    for (int i = 0; i < 4; i++) {
      int row = i * 32 + srow;
      GLD_LDS(Abase + (long long)row * p.lda + k0 + scol, &As[row * 64 + scol]);
    }
#pragma unroll
    for (int i = 0; i < 4; i++) {
      int row = i * 32 + srow;
      GLD_LDS(Bbase + (long long)row * p.ldb + k0 + scol, &Bs[row * 64 + scol]);
    }
    __syncthreads();
#pragma unroll
    for (int kk = 0; kk < 2; kk++) {
      bf16x8 af[4], bfr[4];
      const int kb = kk * 32 + 8 * (lane >> 4);
#pragma unroll
      for (int m = 0; m < 4; m++)
        af[m] = *(const bf16x8*)&As[(wr * 64 + m * 16 + (lane & 15)) * 64 + kb];
#pragma unroll
      for (int n = 0; n < 4; n++)
        bfr[n] = *(const bf16x8*)&Bs[(wc * 64 + n * 16 + (lane & 15)) * 64 + kb];
#pragma unroll
      for (int m = 0; m < 4; m++)
#pragma unroll
        for (int n = 0; n < 4; n++)
          acc[m][n] = __builtin_amdgcn_mfma_f32_16x16x32_bf16(af[m], bfr[n], acc[m][n], 0, 0, 0);
    }
  }

  const int crow0 = m0 + wr * 64, ccol0 = n0 + wc * 64;
#pragma unroll
  for (int m = 0; m < 4; m++) {
#pragma unroll
    for (int n = 0; n < 4; n++) {
      int col = ccol0 + n * 16 + (lane & 15);
#pragma unroll
      for (int q = 0; q < 4; q++) {
        int row = crow0 + m * 16 + (lane >> 4) * 4 + q;
        p.Cb[z * p.c_bs + (long long)row * p.ldc + col] = f2bf(acc[m][n][q]);
      }
    }
  }
}

// ---------------------------------------------------------------- proj (64x128 tile)
// Grid 768 (XCD-swizzled): bn in [0,6) selects k/v/q + 128-col half; bm in [0,128)
// is a 64-row slab (chunk z = bm>>1, j-half = bm&1). 4 waves, wave cols wv*32..+32.
__global__ __launch_bounds__(256)
void proj_kernel(const unsigned short* __restrict__ x16, const unsigned short* __restrict__ w16,
                 const float* __restrict__ bk, const float* __restrict__ bv,
                 const float* __restrict__ bq, const float* __restrict__ gate,
                 const float* __restrict__ decay_ptr,
                 unsigned short* __restrict__ o_v, unsigned short* __restrict__ o_qd,
                 unsigned short* __restrict__ o_kT, unsigned short* __restrict__ o_vTw) {
  __shared__ unsigned short As[64 * 64];    // 8KB
  __shared__ unsigned short Bs[128 * 64];   // 16KB; reused as 128x64 transpose buf
  __shared__ float warr[64];
  const int tid = threadIdx.x;
  const int bid = (blockIdx.x & 7) * (gridDim.x >> 3) + (blockIdx.x >> 3);
  const int bn = bid % 6, bm = bid / 6;
  const int m0 = bm * 64, n0 = bn * 128;
  const int lane = tid & 63, wv = tid >> 6;
  const int srow = tid >> 3, scol = (tid & 7) * 8;   // srow 0..31

  f32x4 acc[4][2] = {};
  const unsigned short* Abase = x16 + (long long)m0 * 1024;
  const unsigned short* Bbase = w16 + (long long)n0 * 1024;

  for (int k0 = 0; k0 < 1024; k0 += 64) {
    if (k0) __syncthreads();
#pragma unroll
    for (int i = 0; i < 2; i++) {
      int row = i * 32 + srow;
      GLD_LDS(Abase + (long long)row * 1024 + k0 + scol, &As[row * 64 + scol]);
    }
#pragma unroll
    for (int i = 0; i < 4; i++) {
      int row = i * 32 + srow;
      GLD_LDS(Bbase + (long long)row * 1024 + k0 + scol, &Bs[row * 64 + scol]);
    }
    __syncthreads();
#pragma unroll
    for (int kk = 0; kk < 2; kk++) {
      const int kb = kk * 32 + 8 * (lane >> 4);
      bf16x8 af[4], bfr[2];
#pragma unroll
      for (int m = 0; m < 4; m++)
        af[m] = *(const bf16x8*)&As[(m * 16 + (lane & 15)) * 64 + kb];
#pragma unroll
      for (int n = 0; n < 2; n++)
        bfr[n] = *(const bf16x8*)&Bs[(wv * 32 + n * 16 + (lane & 15)) * 64 + kb];
#pragma unroll
      for (int m = 0; m < 4; m++)
#pragma unroll
        for (int n = 0; n < 2; n++)
          acc[m][n] = __builtin_amdgcn_mfma_f32_16x16x32_bf16(af[m], bfr[n], acc[m][n], 0, 0, 0);
    }
  }

  const float log2d = log2f(decay_ptr[0]);
  const int sel = bn >> 1;        // 0:k 1:v 2:q
  const int half = bn & 1;        // 128-col half of d_mem
  const int z = bm >> 1, jbase = (bm & 1) * 64;

  if (sel < 2) {
    __syncthreads();              // all waves done with As/Bs fragments
    if (sel == 1 && tid < 64)
      warr[tid] = gate[z * 128 + jbase + tid] * exp2f((float)(127 - (jbase + tid)) * log2d);
  }

#pragma unroll
  for (int m = 0; m < 4; m++) {
#pragma unroll
    for (int n = 0; n < 2; n++) {
      int cl = wv * 32 + n * 16 + (lane & 15);   // local col 0..127
      int r0 = m * 16 + (lane >> 4) * 4;         // local row base 0..63
      float bias = (sel == 0) ? bk[half * 128 + cl]
                 : (sel == 1) ? bv[half * 128 + cl]
                 : bq[half * 128 + cl];
      if (sel < 2) {
        u16x4 pk;
#pragma unroll
        for (int q = 0; q < 4; q++) {
          float v = acc[m][n][q] + bias;
          pk[q] = f2bf(v);
          if (sel == 1)
            o_v[((long long)m0 + r0 + q) * 256 + half * 128 + cl] = pk[q];
        }
        int byteoff = (cl * 128 + r0 * 2) ^ ((cl & 7) << 4);
        *(u16x4*)((char*)Bs + byteoff) = pk;
      } else {
#pragma unroll
        for (int q = 0; q < 4; q++) {
          long long row = m0 + r0 + q;
          float v = acc[m][n][q] + bias;
          o_qd[row * 256 + half * 128 + cl] =
              f2bf(v * exp2f((float)(jbase + r0 + q) * log2d));
        }
      }
    }
  }

  if (sel < 2) {
    __syncthreads();
    unsigned short* dst = (sel == 0 ? o_kT : o_vTw) + (long long)z * 32768;
#pragma unroll
    for (int pp = 0; pp < 4; pp++) {
      int idx = pp * 256 + tid;    // 0..1023
      int c = idx >> 3;            // local col (d) 0..127
      int j0 = (idx & 7) * 8;      // row-run start 0..56
      u16x8 o = *(const u16x8*)((char*)Bs + ((c * 128 + j0 * 2) ^ ((c & 7) << 4)));
      if (sel == 1) {
#pragma unroll
        for (int t = 0; t < 8; t++) o[t] = f2bf(bf2f(o[t]) * warr[j0 + t]);
      }
      *(u16x8*)&dst[(long long)(half * 128 + c) * 128 + jbase + j0] = o;
    }
  }
}

// ---------------------------------------------------------------- y GEMM (64x128 tile)
// out_y[8192][1024] = mo16[8192][256] @ wot16[1024][256]^T + bo. Grid 1024, XCD-swizzled.
__global__ __launch_bounds__(256)
void y64_kernel(const unsigned short* __restrict__ mo16, const unsigned short* __restrict__ wot16,
                const float* __restrict__ bo, float* __restrict__ out_y) {
  __shared__ unsigned short As[64 * 64];    // 8KB
  __shared__ unsigned short Bs[128 * 64];   // 16KB
  const int tid = threadIdx.x;
  const int bid = (blockIdx.x & 7) * (gridDim.x >> 3) + (blockIdx.x >> 3);
  const int bn = bid & 7, bm = bid >> 3;
  const int m0 = bm * 64, n0 = bn * 128;
  const int lane = tid & 63, wv = tid >> 6;
  const int srow = tid >> 3, scol = (tid & 7) * 8;

  f32x4 acc[4][2] = {};
  const unsigned short* Abase = mo16 + (long long)m0 * 256;
  const unsigned short* Bbase = wot16 + (long long)n0 * 256;

  for (int k0 = 0; k0 < 256; k0 += 64) {
    if (k0) __syncthreads();
#pragma unroll
    for (int i = 0; i < 2; i++) {
      int row = i * 32 + srow;
      GLD_LDS(Abase + (long long)row * 256 + k0 + scol, &As[row * 64 + scol]);
    }
#pragma unroll
    for (int i = 0; i < 4; i++) {
      int row = i * 32 + srow;
      GLD_LDS(Bbase + (long long)row * 256 + k0 + scol, &Bs[row * 64 + scol]);
    }
    __syncthreads();
#pragma unroll
    for (int kk = 0; kk < 2; kk++) {
      const int kb = kk * 32 + 8 * (lane >> 4);
      bf16x8 af[4], bfr[2];
#pragma unroll
      for (int m = 0; m < 4; m++)
        af[m] = *(const bf16x8*)&As[(m * 16 + (lane & 15)) * 64 + kb];
#pragma unroll
      for (int n = 0; n < 2; n++)
        bfr[n] = *(const bf16x8*)&Bs[(wv * 32 + n * 16 + (lane & 15)) * 64 + kb];
#pragma unroll
      for (int m = 0; m < 4; m++)
#pragma unroll
        for (int n = 0; n < 2; n++)
          acc[m][n] = __builtin_amdgcn_mfma_f32_16x16x32_bf16(af[m], bfr[n], acc[m][n], 0, 0, 0);
    }
  }

#pragma unroll
  for (int m = 0; m < 4; m++) {
#pragma unroll
    for (int n = 0; n < 2; n++) {
      int col = n0 + wv * 32 + n * 16 + (lane & 15);
      float b = bo[col];
#pragma unroll
      for (int q = 0; q < 4; q++) {
        int row = m0 + m * 16 + (lane >> 4) * 4 + q;
        out_y[(long long)row * 1024 + col] = acc[m][n][q] + b;
      }
    }
  }
}

// ---------------------------------------------------------------- fused chunk attention
__global__ __launch_bounds__(512)
void chunk_attn(const unsigned short* __restrict__ qd16, const unsigned short* __restrict__ v16,
                const unsigned short* __restrict__ kT16, const unsigned short* __restrict__ T16,
                unsigned short* __restrict__ mo16, const float* __restrict__ gbuf,
                const float* __restrict__ decay_ptr) {
  __shared__ unsigned short As[64 * 64];        // qd rows (8KB)
  __shared__ unsigned short Bs[2 * 128 * 64];   // v | T (32KB); reused for kT
  __shared__ unsigned short Al[64 * 128];       // swizzled scores (16KB)
  const int tid = threadIdx.x, lane = tid & 63, wv = tid >> 6;
  const int wr = wv >> 2, wc = wv & 3;          // 2 x 4 wave grid
  const int nh = blockIdx.x, rh = blockIdx.y, z = blockIdx.z;
  const int roff = rh * 64;
  const int srow = tid >> 3, scol = (tid & 7) * 8;
  const float log2d = log2f(decay_ptr[0]);

  const unsigned short* qz = qd16 + (long long)z * 32768 + (long long)roff * 256;
  const unsigned short* vz = v16 + (long long)z * 32768;
  const unsigned short* Tz = T16 + (long long)z * 65536 + (long long)nh * 128 * 256;
  const unsigned short* kz = kT16 + (long long)z * 32768 + (long long)nh * 128 * 128;

  f32x4 acc1[2][2] = {};
  f32x4 acc2[2][2] = {};

  // ---- fused phase 1 (scores) + phase 2a (qd@T^T), K=256 ----
  for (int k0 = 0; k0 < 256; k0 += 64) {
    if (k0) __syncthreads();
    GLD_LDS(qz + (long long)srow * 256 + k0 + scol, &As[srow * 64 + scol]);
#pragma unroll
    for (int i = 0; i < 2; i++) {
      int row = i * 64 + srow;
      GLD_LDS(vz + (long long)row * 256 + k0 + scol, &Bs[row * 64 + scol]);
      GLD_LDS(Tz + (long long)row * 256 + k0 + scol, &Bs[8192 + row * 64 + scol]);
    }
    __syncthreads();
#pragma unroll
    for (int kk = 0; kk < 2; kk++) {
      const int kb = kk * 32 + 8 * (lane >> 4);
      bf16x8 af[2], bv[2], bt[2];
#pragma unroll
      for (int m = 0; m < 2; m++)
        af[m] = *(const bf16x8*)&As[(wr * 32 + m * 16 + (lane & 15)) * 64 + kb];
#pragma unroll
      for (int n = 0; n < 2; n++) {
        bv[n] = *(const bf16x8*)&Bs[(wc * 32 + n * 16 + (lane & 15)) * 64 + kb];
        bt[n] = *(const bf16x8*)&Bs[8192 + (wc * 32 + n * 16 + (lane & 15)) * 64 + kb];
      }
#pragma unroll
      for (int m = 0; m < 2; m++)
#pragma unroll
        for (int n = 0; n < 2; n++) {
          acc1[m][n] = __builtin_amdgcn_mfma_f32_16x16x32_bf16(af[m], bv[n], acc1[m][n], 0, 0, 0);
          acc2[m][n] = __builtin_amdgcn_mfma_f32_16x16x32_bf16(af[m], bt[n], acc2[m][n], 0, 0, 0);
        }
    }
  }

  // ---- scores epilogue -> Al (mask, gate-scale, bf16, swizzled) ----
#pragma unroll
  for (int n = 0; n < 2; n++) {
    int col = wc * 32 + n * 16 + (lane & 15);   // j in [0,128)
    float gsc = gbuf[z * 128 + col] * exp2f(-(float)(col + 1) * log2d);
#pragma unroll
    for (int m = 0; m < 2; m++) {
#pragma unroll
      for (int q = 0; q < 4; q++) {
        int r = wr * 32 + m * 16 + (lane >> 4) * 4 + q;   // local row
        float v = (col < roff + r) ? acc1[m][n][q] * gsc : 0.f;
        int byteoff = (r * 256 + col * 2) ^ ((r & 7) << 4);
        *(unsigned short*)((char*)Al + byteoff) = f2bf(v);
      }
    }
  }
  __syncthreads();   // Al visible; all waves done with Bs

  // ---- phase 2b: acc2 += A @ kT^T, K=128 ----
  for (int k0 = 0; k0 < 128; k0 += 64) {
    if (k0) __syncthreads();
#pragma unroll
    for (int i = 0; i < 2; i++) {
      int row = i * 64 + srow;
      GLD_LDS(kz + (long long)row * 128 + k0 + scol, &Bs[row * 64 + scol]);
    }
    __syncthreads();
#pragma unroll
    for (int kk = 0; kk < 2; kk++) {
      const int kbb = k0 + kk * 32 + 8 * (lane >> 4);
      bf16x8 af[2], bk_[2];
#pragma unroll
      for (int m = 0; m < 2; m++) {
        int r = wr * 32 + m * 16 + (lane & 15);
        af[m] = *(const bf16x8*)((char*)Al + ((r * 256 + kbb * 2) ^ ((r & 7) << 4)));
      }
#pragma unroll
      for (int n = 0; n < 2; n++)
        bk_[n] = *(const bf16x8*)&Bs[(wc * 32 + n * 16 + (lane & 15)) * 64 + kk * 32 + 8 * (lane >> 4)];
#pragma unroll
      for (int m = 0; m < 2; m++)
#pragma unroll
        for (int n = 0; n < 2; n++)
          acc2[m][n] = __builtin_amdgcn_mfma_f32_16x16x32_bf16(af[m], bk_[n], acc2[m][n], 0, 0, 0);
    }
  }

  // ---- store mo ----
#pragma unroll
  for (int m = 0; m < 2; m++) {
#pragma unroll
    for (int n = 0; n < 2; n++) {
      int col = nh * 128 + wc * 32 + n * 16 + (lane & 15);
#pragma unroll
      for (int q = 0; q < 4; q++) {
        int row = roff + wr * 32 + m * 16 + (lane >> 4) * 4 + q;
        mo16[((long long)z * 128 + row) * 256 + col] = f2bf(acc2[m][n][q]);
      }
    }
  }
}

// ---------------------------------------------------------------- prep (cast+gate+weight transposes)
__global__ __launch_bounds__(256)
void prep_kernel(const float* __restrict__ x, const float* __restrict__ Wg,
                 const float* __restrict__ bg, unsigned short* __restrict__ x16,
                 float* __restrict__ g,
                 const float* __restrict__ Wk, const float* __restrict__ Wv,
                 const float* __restrict__ Wq, unsigned short* __restrict__ w16,
                 const float* __restrict__ Wo, unsigned short* __restrict__ wot16) {
  __shared__ float tile[64][65];
  const int bx = blockIdx.x;
  const int tid = threadIdx.x;
  if (bx < 2048) {
    const int wave = tid >> 6, lane = tid & 63;
    const long long row = (long long)bx * 4 + wave;
    const float* xr = x + row * 1024 + lane * 16;
    const float* wr = Wg + lane * 16;
    float s = 0.f;
    u16x8 o0, o1;
#pragma unroll
    for (int qq = 0; qq < 2; qq++) {
      float4 a = *(const float4*)(xr + qq * 4);
      float4 w = *(const float4*)(wr + qq * 4);
      s = fmaf(a.x, w.x, s); s = fmaf(a.y, w.y, s);
      s = fmaf(a.z, w.z, s); s = fmaf(a.w, w.w, s);
      o0[qq * 4 + 0] = f2bf(a.x); o0[qq * 4 + 1] = f2bf(a.y);
      o0[qq * 4 + 2] = f2bf(a.z); o0[qq * 4 + 3] = f2bf(a.w);
    }
#pragma unroll
    for (int qq = 0; qq < 2; qq++) {
      float4 a = *(const float4*)(xr + 8 + qq * 4);
      float4 w = *(const float4*)(wr + 8 + qq * 4);
      s = fmaf(a.x, w.x, s); s = fmaf(a.y, w.y, s);
      s = fmaf(a.z, w.z, s); s = fmaf(a.w, w.w, s);
      o1[qq * 4 + 0] = f2bf(a.x); o1[qq * 4 + 1] = f2bf(a.y);
      o1[qq * 4 + 2] = f2bf(a.z); o1[qq * 4 + 3] = f2bf(a.w);
    }
    *(u16x8*)(x16 + row * 1024 + lane * 16) = o0;
    *(u16x8*)(x16 + row * 1024 + lane * 16 + 8) = o1;
#pragma unroll
    for (int off = 32; off; off >>= 1) s += __shfl_xor(s, off, 64);
    if (lane == 0) g[row] = 1.f / (1.f + expf(-(s + bg[0])));
    return;
  }
  int t = bx - 2048;
  const float* S; unsigned short* dst;
  int srcCols, dstLd, k0, n0g, n0;
  if (t < 192) {
    k0 = (t % 16) * 64; n0g = (t / 16) * 64;
    int sel = n0g >> 8; n0 = n0g - (sel << 8);
    S = sel == 0 ? Wk : sel == 1 ? Wv : Wq;
    srcCols = 256; dst = w16; dstLd = 1024;
  } else {
    t -= 192;
    k0 = (t % 4) * 64; n0g = (t / 4) * 64; n0 = n0g;
    S = Wo; srcCols = 1024; dst = wot16; dstLd = 256;
  }
  const int rr = tid >> 4, c4 = (tid & 15) * 4;
#pragma unroll
  for (int pp = 0; pp < 4; pp++) {
    int r = pp * 16 + rr;
    float4 v = *(const float4*)&S[(long long)(k0 + r) * srcCols + n0 + c4];
    tile[r][c4 + 0] = v.x; tile[r][c4 + 1] = v.y; tile[r][c4 + 2] = v.z; tile[r][c4 + 3] = v.w;
  }
  __syncthreads();
  const int rn = tid >> 3, ck0 = (tid & 7) * 8;
#pragma unroll
  for (int pp = 0; pp < 2; pp++) {
    int n = pp * 32 + rn;
    u16x8 o;
#pragma unroll
    for (int j = 0; j < 8; j++) o[j] = f2bf(tile[ck0 + j][n]);
    *(u16x8*)&dst[(long long)(n0g + n) * dstLd + k0 + ck0] = o;
  }
}

// ---------------------------------------------------------------- chunk-state scan
__global__ __launch_bounds__(256)
void scan_kernel(const unsigned short* __restrict__ Ut16, const float* __restrict__ state_in,
                 unsigned short* __restrict__ T16, float* __restrict__ final_out,
                 const float* __restrict__ decay_ptr) {
  int t = blockIdx.x * 256 + threadIdx.x;   // 0..262143
  int b = t >> 16, pidx = t & 65535;        // pidx = e*256+d
  int e = pidx >> 8, d = pidx & 255;
  float dC = exp2f(128.f * log2f(decay_ptr[0]));
  float cur = state_in[(long long)b * 65536 + d * 256 + e];
#pragma unroll
  for (int c = 0; c < 16; c++) {
    long long off = ((long long)(b * 16 + c)) * 65536 + pidx;
    T16[off] = f2bf(cur);
    cur = fmaf(dC, cur, bf2f(Ut16[off]));
  }
  final_out[(long long)b * 65536 + d * 256 + e] = cur;
}

// ---------------------------------------------------------------- launch
extern "C" void kernel_launch(void* const* d_in, const int* in_sizes, int n_in,
                              void* d_out, int out_size, void* d_ws, size_t ws_size,
                              hipStream_t stream) {
  const float* x     = (const float*)d_in[0];
  const float* state = (const float*)d_in[1];
  const float* Wk = (const float*)d_in[2];  const float* bk = (const float*)d_in[3];
  const float* Wv = (const float*)d_in[4];  const float* bv = (const float*)d_in[5];
  const float* Wq = (const float*)d_in[6];  const float* bq = (const float*)d_in[7];
  const float* Wo = (const float*)d_in[8];  const float* bo = (const float*)d_in[9];
  const float* Wg = (const float*)d_in[10]; const float* bg = (const float*)d_in[11];
  const float* decay = (const float*)d_in[12];

  float* out_y = (float*)d_out;              // [4][2048][1024]
  float* out_S = out_y + 8388608;            // [4][256][256]

  float* ws = (float*)d_ws;
  unsigned short* x16   = (unsigned short*)(ws);             // [8192][1024]
  unsigned short* v16   = (unsigned short*)(ws + 4194304);   // [8192][256]
  unsigned short* qd16  = (unsigned short*)(ws + 5242880);   // [8192][256] (q * d^i)
  unsigned short* w16   = (unsigned short*)(ws + 6291456);   // [768][1024]
  unsigned short* wot16 = (unsigned short*)(ws + 6684672);   // [1024][256]
  float*          gbuf  = ws + 6815744;                      // [8192]
  unsigned short* kT16  = (unsigned short*)(ws + 6823936);   // [64][256][128]
  unsigned short* vTw16 = (unsigned short*)(ws + 7872512);   // [64][256][128]
  unsigned short* Ut16  = (unsigned short*)(ws + 8921088);   // [64][256][256]
  unsigned short* T16   = (unsigned short*)(ws + 11018240);  // [64][256][256]
  unsigned short* mo16  = (unsigned short*)(ws + 13115392);  // [8192][256]

  // 1. prep: cast+gate + weight transposes
  prep_kernel<<<2304, 256, 0, stream>>>(x, Wg, bg, x16, gbuf, Wk, Wv, Wq, w16, Wo, wot16);

  // 2. proj (64x128 tiles, 768 blocks, XCD-swizzled) -> v16, qd16, kT16, vTw16
  proj_kernel<<<768, 256, 0, stream>>>(x16, w16, bk, bv, bq, gbuf, decay,
                                       v16, qd16, kT16, vTw16);

  // 3. Ut[z] = kT @ vTw^T -> bf16
  {
    MP p{};
    p.A = kT16;  p.a_bs = 32768; p.lda = 128;
    p.B = vTw16; p.b_bs = 32768; p.ldb = 128;
    p.K = 128; p.grid_n = 2;
    p.Cb = Ut16; p.c_bs = 65536; p.ldc = 256;
    gemm_ut<<<dim3(4, 1, 64), 256, 0, stream>>>(p);
  }

  // 4. chunk-state scan -> T16 + final_state
  scan_kernel<<<1024, 256, 0, stream>>>(Ut16, state, T16, out_S, decay);

  // 5. fused scores + mem_out
  chunk_attn<<<dim3(2, 2, 64), 512, 0, stream>>>(qd16, v16, kT16, T16, mo16, gbuf, decay);

  // 6. y = mo16 @ wot16^T + bo  (64x128 tiles, 1024 blocks, XCD-swizzled)
  y64_kernel<<<1024, 256, 0, stream>>>(mo16, wot16, bo, out_y);
}